// Round 5
// baseline (419.195 us; speedup 1.0000x reference)
//
#include <hip/hip_runtime.h>

typedef _Float16 half8 __attribute__((ext_vector_type(8)));
typedef _Float16 half4 __attribute__((ext_vector_type(4)));
typedef short short8 __attribute__((ext_vector_type(8)));
typedef unsigned short ushort4v __attribute__((ext_vector_type(4)));
typedef float floatx4 __attribute__((ext_vector_type(4)));

#define ASYNC16(g, l) __builtin_amdgcn_global_load_lds( \
    (const __attribute__((address_space(1))) void*)(g),  \
    (__attribute__((address_space(3))) void*)(l), 16, 0, 0)

__device__ inline unsigned short f2bf(float f) {          // RNE fp32->bf16
    unsigned u = __builtin_bit_cast(unsigned, f);
    u += 0x7fff + ((u >> 16) & 1);
    return (unsigned short)(u >> 16);
}

// ---------------------------------------------------------------------------
// fp32 -> fp16 bulk convert (vectorized, grid-stride)
// ---------------------------------------------------------------------------
__global__ void cvt_f2h(const float* __restrict__ in, _Float16* __restrict__ out, int n4)
{
    int i = blockIdx.x * blockDim.x + threadIdx.x;
    const int stride = gridDim.x * blockDim.x;
    for (; i < n4; i += stride) {
        float4 v = ((const float4*)in)[i];
        half4 h = { (_Float16)v.x, (_Float16)v.y, (_Float16)v.z, (_Float16)v.w };
        ((half4*)out)[i] = h;
    }
}

// ---------------------------------------------------------------------------
// W [K=1024][N=1024] fp32  ->  Wt [N][K] fp16   (z = which of Wq/Wk/Wv)
// ---------------------------------------------------------------------------
__global__ void transpose_w(const float* __restrict__ Wq, const float* __restrict__ Wk,
                            const float* __restrict__ Wv, _Float16* __restrict__ Wt)
{
    const float* W = (blockIdx.z == 0) ? Wq : (blockIdx.z == 1) ? Wk : Wv;
    _Float16* out = Wt + (size_t)blockIdx.z * 1024 * 1024;
    __shared__ float t[32][33];
    const int tx = threadIdx.x, ty = threadIdx.y;     // (32,8)
    const int k0 = blockIdx.x * 32, n0 = blockIdx.y * 32;
#pragma unroll
    for (int i = 0; i < 32; i += 8)
        t[ty + i][tx] = W[(size_t)(k0 + ty + i) * 1024 + n0 + tx];   // t[k][n]
    __syncthreads();
#pragma unroll
    for (int i = 0; i < 32; i += 8)
        out[(size_t)(n0 + ty + i) * 1024 + k0 + tx] = (_Float16)t[tx][ty + i];  // out[n][k]=W[k][n]
}

// ---------------------------------------------------------------------------
// QKV GEMM: C[16384 x 3072] = xh[16384x1024] @ [Wq|Wk|Wv] + bias
//   128x128 tile, BK=64, XOR-swizzled LDS (zero bank conflicts — R3)
//   epilogue: Q,K row-major fp16; V transposed per batch, BF16 (Vt[b][d][s])
// ---------------------------------------------------------------------------
__global__ __launch_bounds__(256, 2)
void gemm_qkv(const _Float16* __restrict__ X, const _Float16* __restrict__ Wt,
              const float* __restrict__ bq, const float* __restrict__ bk,
              const float* __restrict__ bv,
              _Float16* __restrict__ Qh, _Float16* __restrict__ Kh,
              unsigned short* __restrict__ Vt)
{
    __shared__ __align__(16) _Float16 sA[128 * 64];
    __shared__ __align__(16) _Float16 sB[128 * 64];
    const int tid = threadIdx.x;
    const int lane = tid & 63, wave = tid >> 6;
    const int quad = lane >> 4, l15 = lane & 15;
    const int wm = (wave & 1) * 64, wn = (wave >> 1) * 64;
    const long m0 = (long)blockIdx.y * 128;
    const int  n0 = blockIdx.x * 128;

    const _Float16* Ab = X + m0 * 1024;
    const _Float16* Bb = Wt + (long)n0 * 1024;

    long offA[4];
    int ldsOff[4];
#pragma unroll
    for (int u = 0; u < 4; ++u) {
        const int c = tid + u * 256;
        const int row = c >> 3, g = (c & 7) ^ (row & 7);
        offA[u] = (long)row * 1024 + g * 8;
        ldsOff[u] = c * 16;
    }
    const int sw = l15 & 7;

    floatx4 acc[4][4] = {};

    for (int k0 = 0; k0 < 1024; k0 += 64) {
        __syncthreads();
#pragma unroll
        for (int u = 0; u < 4; ++u) {
            ASYNC16(Ab + offA[u] + k0, (char*)sA + ldsOff[u]);
            ASYNC16(Bb + offA[u] + k0, (char*)sB + ldsOff[u]);
        }
        __syncthreads();
#pragma unroll
        for (int s = 0; s < 2; ++s) {
            const int ck = ((s * 4 + quad) ^ sw) * 8;
            half8 af[4], bf[4];
#pragma unroll
            for (int i = 0; i < 4; ++i) {
                af[i] = *(const half8*)(sA + (wm + i * 16 + l15) * 64 + ck);
                bf[i] = *(const half8*)(sB + (wn + i * 16 + l15) * 64 + ck);
            }
#pragma unroll
            for (int i = 0; i < 4; ++i)
#pragma unroll
                for (int j = 0; j < 4; ++j)
                    acc[i][j] = __builtin_amdgcn_mfma_f32_16x16x32_f16(af[i], bf[j], acc[i][j], 0, 0, 0);
        }
    }

    const int which = n0 >> 10;           // 0=Q 1=K 2=V
    const int ncol0 = n0 & 1023;
    const float* bias = (which == 0) ? bq : (which == 1) ? bk : bv;

    if (which < 2) {
        _Float16* O = which ? Kh : Qh;
#pragma unroll
        for (int i = 0; i < 4; ++i) {
            const long mb = m0 + wm + i * 16 + quad * 4;
#pragma unroll
            for (int j = 0; j < 4; ++j) {
                const int col = ncol0 + wn + j * 16 + l15;
                const float bb = bias[col];
                _Float16* op = O + mb * 1024 + col;
#pragma unroll
                for (int r = 0; r < 4; ++r)
                    op[(long)r * 1024] = (_Float16)(acc[i][j][r] + bb);
            }
        }
    } else {
#pragma unroll
        for (int i = 0; i < 4; ++i) {
            const long mb = m0 + wm + i * 16 + quad * 4;
            const int b = (int)(mb >> 11);
            const int s = (int)(mb & 2047);
#pragma unroll
            for (int j = 0; j < 4; ++j) {
                const int col = ncol0 + wn + j * 16 + l15;
                const float bb = bias[col];
                ushort4v h;
#pragma unroll
                for (int r = 0; r < 4; ++r) h[r] = f2bf(acc[i][j][r] + bb);
                *(ushort4v*)(Vt + (long)b * 2097152 + (long)col * 2048 + s) = h;
            }
        }
    }
}

// ---------------------------------------------------------------------------
// Scores GEMM + fused exp: E[z][m][n] = exp(Q_m . K_n - 40) in bf16.
//   No rowsum here — pv recomputes it via ones-MFMA (saves the 64KB buffer
//   that pushed the ws footprint 64KB past 160 MiB and forced chunking).
// ---------------------------------------------------------------------------
__global__ __launch_bounds__(256, 2)
void gemm_sc(const _Float16* __restrict__ Q, const _Float16* __restrict__ K,
             unsigned short* __restrict__ E)
{
    __shared__ __align__(16) _Float16 sA[128 * 64];
    __shared__ __align__(16) _Float16 sB[128 * 64];
    const int tid = threadIdx.x;
    const int lane = tid & 63, wave = tid >> 6;
    const int quad = lane >> 4, l15 = lane & 15;
    const int wm = (wave & 1) * 64, wn = (wave >> 1) * 64;
    const long m0 = (long)blockIdx.y * 128;
    const long n0 = (long)blockIdx.x * 128;

    const _Float16* Ab = Q + (long)blockIdx.z * 2097152 + m0 * 1024;
    const _Float16* Bb = K + (long)blockIdx.z * 2097152 + n0 * 1024;
    unsigned short* Eb = E + (long)blockIdx.z * 4194304;

    long offA[4];
    int ldsOff[4];
#pragma unroll
    for (int u = 0; u < 4; ++u) {
        const int c = tid + u * 256;
        const int row = c >> 3, g = (c & 7) ^ (row & 7);
        offA[u] = (long)row * 1024 + g * 8;
        ldsOff[u] = c * 16;
    }
    const int sw = l15 & 7;

    floatx4 acc[4][4] = {};

    for (int k0 = 0; k0 < 1024; k0 += 64) {
        __syncthreads();
#pragma unroll
        for (int u = 0; u < 4; ++u) {
            ASYNC16(Ab + offA[u] + k0, (char*)sA + ldsOff[u]);
            ASYNC16(Bb + offA[u] + k0, (char*)sB + ldsOff[u]);
        }
        __syncthreads();
#pragma unroll
        for (int s = 0; s < 2; ++s) {
            const int ck = ((s * 4 + quad) ^ sw) * 8;
            half8 af[4], bf[4];
#pragma unroll
            for (int i = 0; i < 4; ++i) {
                af[i] = *(const half8*)(sA + (wm + i * 16 + l15) * 64 + ck);
                bf[i] = *(const half8*)(sB + (wn + i * 16 + l15) * 64 + ck);
            }
#pragma unroll
            for (int i = 0; i < 4; ++i)
#pragma unroll
                for (int j = 0; j < 4; ++j)
                    acc[i][j] = __builtin_amdgcn_mfma_f32_16x16x32_f16(af[i], bf[j], acc[i][j], 0, 0, 0);
        }
    }

    // epilogue: E = exp(score - 40) in bf16 (constant shift replaces row max;
    // bf16 shares fp32 exponent range so no underflow for weak rows)
#pragma unroll
    for (int i = 0; i < 4; ++i) {
        const int rowb = (int)(m0 + wm + i * 16 + quad * 4);
#pragma unroll
        for (int r = 0; r < 4; ++r) {
#pragma unroll
            for (int j = 0; j < 4; ++j) {
                const long col = n0 + wn + j * 16 + l15;
                Eb[(long)(rowb + r) * 2048 + col] = f2bf(__expf(acc[i][j][r] - 40.0f));
            }
        }
    }
}

// ---------------------------------------------------------------------------
// Context GEMM (bf16): out[z][m][d] = (sum_k E[m][k] * Vt[d][k]) / rowsum_m
//   rowsum computed in-kernel: accS[i] = mfma(af[i], ones, accS[i])
//   A=E bf16 lda=2048, B=Vt bf16 ldb=2048, K=2048; C fp32 ldc=1024
// ---------------------------------------------------------------------------
__global__ __launch_bounds__(256, 2)
void gemm_pv(const unsigned short* __restrict__ E, const unsigned short* __restrict__ Vt,
             float* __restrict__ C)
{
    __shared__ __align__(16) unsigned short sA[128 * 64];
    __shared__ __align__(16) unsigned short sB[128 * 64];
    const int tid = threadIdx.x;
    const int lane = tid & 63, wave = tid >> 6;
    const int quad = lane >> 4, l15 = lane & 15;
    const int wm = (wave & 1) * 64, wn = (wave >> 1) * 64;
    const long m0 = (long)blockIdx.y * 128;
    const long n0 = (long)blockIdx.x * 128;

    const unsigned short* Ab = E + (long)blockIdx.z * 4194304 + m0 * 2048;
    const unsigned short* Bb = Vt + (long)blockIdx.z * 2097152 + n0 * 2048;
    float* Cb = C + (long)blockIdx.z * 2097152;

    long offA[4];
    int ldsOff[4];
#pragma unroll
    for (int u = 0; u < 4; ++u) {
        const int c = tid + u * 256;
        const int row = c >> 3, g = (c & 7) ^ (row & 7);
        offA[u] = (long)row * 2048 + g * 8;
        ldsOff[u] = c * 16;
    }
    const int sw = l15 & 7;

    short8 ones;
#pragma unroll
    for (int r = 0; r < 8; ++r) ones[r] = (short)0x3F80;   // bf16 1.0

    floatx4 acc[4][4] = {};
    floatx4 accS[4] = {};   // row sums (every col identical)

    for (int k0 = 0; k0 < 2048; k0 += 64) {
        __syncthreads();
#pragma unroll
        for (int u = 0; u < 4; ++u) {
            ASYNC16(Ab + offA[u] + k0, (char*)sA + ldsOff[u]);
            ASYNC16(Bb + offA[u] + k0, (char*)sB + ldsOff[u]);
        }
        __syncthreads();
#pragma unroll
        for (int s = 0; s < 2; ++s) {
            const int ck = ((s * 4 + quad) ^ sw) * 8;
            short8 af[4], bf[4];
#pragma unroll
            for (int i = 0; i < 4; ++i) {
                af[i] = *(const short8*)(sA + (wm + i * 16 + l15) * 64 + ck);
                bf[i] = *(const short8*)(sB + (wn + i * 16 + l15) * 64 + ck);
            }
#pragma unroll
            for (int i = 0; i < 4; ++i) {
                accS[i] = __builtin_amdgcn_mfma_f32_16x16x32_bf16(af[i], ones, accS[i], 0, 0, 0);
#pragma unroll
                for (int j = 0; j < 4; ++j)
                    acc[i][j] = __builtin_amdgcn_mfma_f32_16x16x32_bf16(af[i], bf[j], acc[i][j], 0, 0, 0);
            }
        }
    }

#pragma unroll
    for (int i = 0; i < 4; ++i) {
        const int rowb = (int)(m0 + wm + i * 16 + quad * 4);
#pragma unroll
        for (int r = 0; r < 4; ++r) {
            const float inv = 1.0f / accS[i][r];
            float* cp = Cb + (long)(rowb + r) * 1024 + n0 + wn + l15;
#pragma unroll
            for (int j = 0; j < 4; ++j)
                cp[j * 16] = acc[i][j][r] * inv;
        }
    }
}

// ---------------------------------------------------------------------------
extern "C" void kernel_launch(void* const* d_in, const int* in_sizes, int n_in,
                              void* d_out, int out_size, void* d_ws, size_t ws_size,
                              hipStream_t stream)
{
    const float* x  = (const float*)d_in[0];
    const float* Wq = (const float*)d_in[1];
    const float* bq = (const float*)d_in[2];
    const float* Wk = (const float*)d_in[3];
    const float* bk = (const float*)d_in[4];
    const float* Wv = (const float*)d_in[5];
    const float* bv = (const float*)d_in[6];
    float* out = (float*)d_out;

    char* ws = (char*)d_ws;
    _Float16* Qh = (_Float16*)ws;              // [16384][1024] fp16  (33.5 MB)
    _Float16* Kh = Qh + 16777216;              // [16384][1024] fp16  (33.5 MB)
    unsigned short* Vt = (unsigned short*)(Kh + 16777216);  // 8x[1024][2048] bf16 (33.5 MB)
    char* region = ws + 100663296;             // (xh+Wt) then E
    _Float16* xh = (_Float16*)region;          // [16384][1024] fp16 (dead after QKV)
    _Float16* Wt = xh + 16777216;              // [3072][1024] fp16  (dead after QKV)
    unsigned short* E = (unsigned short*)region;  // c x [2048][2048] bf16 (overwrites xh/Wt)

    // chunk c over batches: region = max(xh+Wt = 39845888, c*8388608)
    // c=8 needs exactly 160 MiB total — no rowsum buffer anymore.
    int c = 8;
    for (;;) {
        size_t region_sz = (size_t)c * 8388608ull;
        if (region_sz < 39845888ull) region_sz = 39845888ull;
        if (100663296ull + region_sz <= ws_size || c == 1) break;
        c >>= 1;
    }

    cvt_f2h<<<2048, 256, 0, stream>>>(x, xh, 16777216 / 4);
    transpose_w<<<dim3(32, 32, 3), dim3(32, 8, 1), 0, stream>>>(Wq, Wk, Wv, Wt);
    gemm_qkv<<<dim3(24, 128, 1), 256, 0, stream>>>(xh, Wt, bq, bk, bv, Qh, Kh, Vt);

    for (int b0 = 0; b0 < 8; b0 += c) {
        int cc = (8 - b0 < c) ? (8 - b0) : c;
        gemm_sc<<<dim3(16, 16, cc), 256, 0, stream>>>(
            Qh + (long)b0 * 2097152, Kh + (long)b0 * 2097152, E);
        gemm_pv<<<dim3(8, 16, cc), 256, 0, stream>>>(
            E, Vt + (long)b0 * 2097152, out + (long)b0 * 2097152);
    }
}